// Round 10
// baseline (302.051 us; speedup 1.0000x reference)
//
#include <hip/hip_runtime.h>
#include <hip/hip_bf16.h>

typedef __hip_bfloat16 bf16;
typedef short bf16x8 __attribute__((ext_vector_type(8)));
typedef float f32x4 __attribute__((ext_vector_type(4)));

// ---------- helpers ----------
__device__ __forceinline__ float b2f_us(unsigned short u) {
    union { unsigned int i; float f; } c;
    c.i = ((unsigned int)u) << 16;
    return c.f;
}
__device__ __forceinline__ unsigned short f2b_us(float f) {
    bf16 h = __float2bfloat16(f);
    return *reinterpret_cast<unsigned short*>(&h);
}
__device__ __forceinline__ void unpack8(uint4 p, float* f) {
    f[0] = b2f_us(p.x & 0xffff); f[1] = b2f_us(p.x >> 16);
    f[2] = b2f_us(p.y & 0xffff); f[3] = b2f_us(p.y >> 16);
    f[4] = b2f_us(p.z & 0xffff); f[5] = b2f_us(p.z >> 16);
    f[6] = b2f_us(p.w & 0xffff); f[7] = b2f_us(p.w >> 16);
}

// async 16B global -> LDS (global_load_lds_dwordx4)
__device__ __forceinline__ void async_copy16(const bf16* g, bf16* l) {
    __builtin_amdgcn_global_load_lds(
        (const __attribute__((address_space(1))) unsigned int*)g,
        (__attribute__((address_space(3))) unsigned int*)l, 16, 0, 0);
}

// ---------- CSR build ----------
__global__ __launch_bounds__(256) void k_count(const int* __restrict__ col,
                                               int* __restrict__ cnt, int E) {
    int e = blockIdx.x * 256 + threadIdx.x;
    if (e < E) atomicAdd(cnt + col[e], 1);
}
__global__ __launch_bounds__(256) void k_rsqrt(const int* __restrict__ cnt,
                                               float* __restrict__ dinv, int N) {
    int i = blockIdx.x * 256 + threadIdx.x;
    if (i < N) dinv[i] = rsqrtf((float)cnt[i] + 1.0f);  // +1 self-loop
}

// ---- hierarchical exclusive scan over N=65536 (256 blocks x 256) ----
__global__ __launch_bounds__(256) void k_scan_a(const int* __restrict__ cnt,
                                                int* __restrict__ bsum) {
    __shared__ int s[256];
    int t = threadIdx.x;
    s[t] = cnt[blockIdx.x * 256 + t];
    __syncthreads();
#pragma unroll
    for (int off = 128; off >= 1; off >>= 1) {
        if (t < off) s[t] += s[t + off];
        __syncthreads();
    }
    if (t == 0) bsum[blockIdx.x] = s[0];
}
__global__ __launch_bounds__(256) void k_scan_b(const int* __restrict__ bsum,
                                                int* __restrict__ boff) {
    __shared__ int s[256];
    int t = threadIdx.x;
    int self = bsum[t];
    s[t] = self;
    __syncthreads();
#pragma unroll
    for (int off = 1; off < 256; off <<= 1) {
        int v = (t >= off) ? s[t - off] : 0;
        __syncthreads();
        s[t] += v;
        __syncthreads();
    }
    boff[t] = s[t] - self;  // exclusive
}
__global__ __launch_bounds__(256) void k_scan_c(const int* __restrict__ cnt,
                                                const int* __restrict__ boff,
                                                int* __restrict__ rowptr) {
    __shared__ int s[256];
    int t = threadIdx.x;
    int base = blockIdx.x * 256;
    int self = cnt[base + t];
    s[t] = self;
    __syncthreads();
#pragma unroll
    for (int off = 1; off < 256; off <<= 1) {
        int v = (t >= off) ? s[t - off] : 0;
        __syncthreads();
        s[t] += v;
        __syncthreads();
    }
    rowptr[base + t] = boff[blockIdx.x] + s[t] - self;  // exclusive
}

__global__ __launch_bounds__(256) void k_scatter(const int* __restrict__ row,
                                                 const int* __restrict__ col,
                                                 const float* __restrict__ dinv,
                                                 const int* __restrict__ rowptr,
                                                 int* __restrict__ fill,
                                                 int2* __restrict__ adj, int E) {
    int e = blockIdx.x * 256 + threadIdx.x;
    if (e >= E) return;
    int r = row[e], c = col[e];
    int pos = rowptr[c] + atomicAdd(fill + c, 1);
    adj[pos] = make_int2(r, __float_as_int(dinv[r]));
}

// ---------- weight prep: W[K,N] f32 -> WT[N,K] bf16 ----------
__global__ __launch_bounds__(256) void k_prep(const float* __restrict__ W,
                                              bf16* __restrict__ WT, int K, int N) {
    int idx = blockIdx.x * 256 + threadIdx.x;
    if (idx >= K * N) return;
    int k = idx / N, n = idx - k * N;
    WT[(size_t)n * K + k] = __float2bfloat16(W[idx]);
}

// ---------- gather on raw x (F=3, f32): agg1 = Ax (normalized, incl. self) ----------
__global__ __launch_bounds__(256) void k_gather_x(const int2* __restrict__ adj,
                                                  const int* __restrict__ rowptr,
                                                  const int* __restrict__ cnt,
                                                  const float* __restrict__ dinv,
                                                  const float* __restrict__ x,
                                                  float* __restrict__ agg1, int N) {
    int n = blockIdx.x * 256 + threadIdx.x;
    if (n >= N) return;
    float d = dinv[n];
    float d2 = d * d;
    float a0 = x[n * 3] * d2, a1 = x[n * 3 + 1] * d2, a2 = x[n * 3 + 2] * d2;
    int beg = rowptr[n], end = beg + cnt[n];
    for (int e = beg; e < end; ++e) {
        int2 ad = adj[e];
        float w = __int_as_float(ad.y) * d;
        a0 += x[ad.x * 3] * w;
        a1 += x[ad.x * 3 + 1] * w;
        a2 += x[ad.x * 3 + 2] * w;
    }
    agg1[n * 3] = a0; agg1[n * 3 + 1] = a1; agg1[n * 3 + 2] = a2;
}

// ---------- layer-1 GEMM: h1 = relu(agg1[N,3] @ W1[3,64] + b1), bf16 out ----------
__global__ __launch_bounds__(256) void k_gemm1(const float* __restrict__ agg1,
                                               const float* __restrict__ W,
                                               const float* __restrict__ bias,
                                               bf16* __restrict__ h1, int M) {
    __shared__ float w[256];
    int t = threadIdx.x;
    if (t < 192) w[t] = W[t];
    if (t >= 192) w[t] = bias[t - 192];
    __syncthreads();
    int idx = blockIdx.x * 256 + t;
    if (idx < M * 64) {
        int n = idx >> 6, f = idx & 63;
        float acc = agg1[n * 3] * w[f] + agg1[n * 3 + 1] * w[64 + f] +
                    agg1[n * 3 + 2] * w[128 + f] + w[192 + f];
        h1[idx] = __float2bfloat16(fmaxf(acc, 0.f));
    }
}

// ---------- CSR gather (bf16 -> bf16, incl. self; 8 feats/lane, 4-edge unroll) ----------
template <int F>
__global__ __launch_bounds__(256) void k_gather_pre(const int2* __restrict__ adj,
                                                    const int* __restrict__ rowptr,
                                                    const int* __restrict__ cnt,
                                                    const float* __restrict__ dinv,
                                                    const bf16* __restrict__ h,
                                                    bf16* __restrict__ agg, int N) {
    constexpr int LPN = F / 8;           // lanes per node, 8 feats (16B) each
    constexpr int NPB = 256 / LPN;       // nodes per block
    int t = threadIdx.x;
    int node = blockIdx.x * NPB + t / LPN;
    if (node >= N) return;
    int fbase = (t % LPN) * 8;
    float d = dinv[node];
    size_t sbase = (size_t)node * F + fbase;
    uint4 sp = *reinterpret_cast<const uint4*>(h + sbase);
    float a[8];
    unpack8(sp, a);
    float d2 = d * d;
#pragma unroll
    for (int i = 0; i < 8; i++) a[i] *= d2;
    int beg = rowptr[node];
    int end = beg + cnt[node];
    int e = beg;
    for (; e + 3 < end; e += 4) {
        int2 ad0 = adj[e], ad1 = adj[e + 1], ad2 = adj[e + 2], ad3 = adj[e + 3];
        const uint4 p0 = *reinterpret_cast<const uint4*>(h + (size_t)ad0.x * F + fbase);
        const uint4 p1 = *reinterpret_cast<const uint4*>(h + (size_t)ad1.x * F + fbase);
        const uint4 p2 = *reinterpret_cast<const uint4*>(h + (size_t)ad2.x * F + fbase);
        const uint4 p3 = *reinterpret_cast<const uint4*>(h + (size_t)ad3.x * F + fbase);
        float w0 = __int_as_float(ad0.y) * d;
        float w1 = __int_as_float(ad1.y) * d;
        float w2 = __int_as_float(ad2.y) * d;
        float w3 = __int_as_float(ad3.y) * d;
        float f0[8], f1[8], f2[8], f3[8];
        unpack8(p0, f0); unpack8(p1, f1); unpack8(p2, f2); unpack8(p3, f3);
#pragma unroll
        for (int i = 0; i < 8; i++)
            a[i] += f0[i] * w0 + f1[i] * w1 + f2[i] * w2 + f3[i] * w3;
    }
    for (; e < end; ++e) {
        int2 ad = adj[e];
        float w = __int_as_float(ad.y) * d;
        uint4 p = *reinterpret_cast<const uint4*>(h + (size_t)ad.x * F + fbase);
        float f[8];
        unpack8(p, f);
#pragma unroll
        for (int i = 0; i < 8; i++) a[i] += f[i] * w;
    }
    uint4 r;
    r.x = (unsigned)f2b_us(a[0]) | ((unsigned)f2b_us(a[1]) << 16);
    r.y = (unsigned)f2b_us(a[2]) | ((unsigned)f2b_us(a[3]) << 16);
    r.z = (unsigned)f2b_us(a[4]) | ((unsigned)f2b_us(a[5]) << 16);
    r.w = (unsigned)f2b_us(a[6]) | ((unsigned)f2b_us(a[7]) << 16);
    *reinterpret_cast<uint4*>(agg + sbase) = r;
}

// ---------- MFMA GEMM + bias + relu: C = relu(A @ BT^T + b), bf16 out ----------
__global__ __launch_bounds__(256) void k_gemm_br(const bf16* __restrict__ A,
                                                 const bf16* __restrict__ BT,
                                                 const float* __restrict__ bias,
                                                 bf16* __restrict__ C,
                                                 int M, int N, int K) {
    __shared__ bf16 As[128 * 32];
    __shared__ bf16 Bs[128 * 32];
    const int t = threadIdx.x;
    const int wave = t >> 6, lane = t & 63;
    const int quad = lane >> 4, l16 = lane & 15;
    const int wm = wave & 1, wn = wave >> 1;
    const int m0 = blockIdx.x * 128;
    const int n0 = blockIdx.y * 128;

    f32x4 acc[4][4] = {};
    for (int kb = 0; kb < K; kb += 32) {
#pragma unroll
        for (int rnd = 0; rnd < 2; ++rnd) {
            int c = (rnd * 4 + wave) * 64 + lane;
            int r = c >> 2, seg = c & 3;
            async_copy16(A + (size_t)(m0 + r) * K + kb + seg * 8, As + c * 8);
            async_copy16(BT + (size_t)(n0 + r) * K + kb + seg * 8, Bs + c * 8);
        }
        __syncthreads();
        bf16x8 af[4], bfr[4];
#pragma unroll
        for (int i = 0; i < 4; i++)
            af[i] = *reinterpret_cast<const bf16x8*>(&As[(wm * 64 + i * 16 + l16) * 32 + quad * 8]);
#pragma unroll
        for (int j = 0; j < 4; j++)
            bfr[j] = *reinterpret_cast<const bf16x8*>(&Bs[(wn * 64 + j * 16 + l16) * 32 + quad * 8]);
#pragma unroll
        for (int i = 0; i < 4; i++)
#pragma unroll
            for (int j = 0; j < 4; j++)
                acc[i][j] = __builtin_amdgcn_mfma_f32_16x16x32_bf16(af[i], bfr[j], acc[i][j], 0, 0, 0);
        __syncthreads();
    }
#pragma unroll
    for (int j = 0; j < 4; j++) {
        int cn = n0 + wn * 64 + j * 16 + l16;
        float bv = bias[cn];
#pragma unroll
        for (int i = 0; i < 4; i++) {
            int row = m0 + wm * 64 + i * 16 + quad * 4;
#pragma unroll
            for (int r = 0; r < 4; r++)
                C[(size_t)(row + r) * N + cn] = __float2bfloat16(fmaxf(acc[i][j][r] + bv, 0.f));
        }
    }
}

// ---------- FUSED layer 3: CSR gather (h2, F=256) -> MFMA (256->512) -> pool partials
// 64 rows/block, 1024 blocks. Gather into registers (4 thr/row x 64 feats, f32),
// pack to LDS As[kchunk][row][32] (m97-style read pattern), then 4 column-chunks
// x 8 K-iters MFMA with Bs staged per iter. No agg3 materialization, no atomics.
__global__ __launch_bounds__(256) void k_gcn3(const int2* __restrict__ adj,
                                              const int* __restrict__ rowptr,
                                              const int* __restrict__ cnt,
                                              const float* __restrict__ dinv,
                                              const bf16* __restrict__ h2,
                                              const bf16* __restrict__ BT,
                                              const float* __restrict__ bias,
                                              float* __restrict__ partials) {
    __shared__ bf16 As[8][64][32];   // 32 KB
    __shared__ bf16 Bs[128 * 32];    // 8 KB
    const int t = threadIdx.x;
    const int m0 = blockIdx.x * 64;

    // ---- gather phase ----
    {
        int row = t >> 2, q = t & 3;
        int fbase = q * 64;
        int node = m0 + row;
        float d = dinv[node];
        float d2 = d * d;
        float a[64];
        const bf16* hrow = h2 + (size_t)node * 256 + fbase;
#pragma unroll
        for (int i = 0; i < 8; i++) {
            uint4 p = *reinterpret_cast<const uint4*>(hrow + i * 8);
            float f[8];
            unpack8(p, f);
#pragma unroll
            for (int j = 0; j < 8; j++) a[i * 8 + j] = f[j] * d2;
        }
        int beg = rowptr[node], end = beg + cnt[node];
        for (int e = beg; e < end; ++e) {
            int2 ad = adj[e];
            float w = __int_as_float(ad.y) * d;
            const bf16* src = h2 + (size_t)ad.x * 256 + fbase;
            uint4 p[8];
#pragma unroll
            for (int i = 0; i < 8; i++)
                p[i] = *reinterpret_cast<const uint4*>(src + i * 8);
#pragma unroll
            for (int i = 0; i < 8; i++) {
                float f[8];
                unpack8(p[i], f);
#pragma unroll
                for (int j = 0; j < 8; j++) a[i * 8 + j] += f[j] * w;
            }
        }
        // pack to LDS: feat f = fbase + i*8 -> chunk f>>5, offset f&31
#pragma unroll
        for (int i = 0; i < 8; i++) {
            int f = fbase + i * 8;
            int c = f >> 5, off = f & 31;
            uint4 r;
            r.x = (unsigned)f2b_us(a[i * 8 + 0]) | ((unsigned)f2b_us(a[i * 8 + 1]) << 16);
            r.y = (unsigned)f2b_us(a[i * 8 + 2]) | ((unsigned)f2b_us(a[i * 8 + 3]) << 16);
            r.z = (unsigned)f2b_us(a[i * 8 + 4]) | ((unsigned)f2b_us(a[i * 8 + 5]) << 16);
            r.w = (unsigned)f2b_us(a[i * 8 + 6]) | ((unsigned)f2b_us(a[i * 8 + 7]) << 16);
            *reinterpret_cast<uint4*>(&As[c][row][off]) = r;
        }
    }
    __syncthreads();

    // ---- MFMA + pool phase ----
    const int wave = t >> 6, lane = t & 63;
    const int quad = lane >> 4, l16 = lane & 15;
    for (int nt = 0; nt < 4; ++nt) {
        f32x4 acc[4][2] = {};
        for (int kc = 0; kc < 8; ++kc) {
            // stage Bs: cols nt*128 + r (r=0..127), k = kc*32..+31
#pragma unroll
            for (int rnd = 0; rnd < 2; ++rnd) {
                int c = (rnd * 4 + wave) * 64 + lane;  // 0..511
                int r = c >> 2, seg = c & 3;
                async_copy16(BT + (size_t)(nt * 128 + r) * 256 + kc * 32 + seg * 8,
                             Bs + c * 8);
            }
            __syncthreads();
            bf16x8 af[4], bfr[2];
#pragma unroll
            for (int i = 0; i < 4; i++)
                af[i] = *reinterpret_cast<const bf16x8*>(&As[kc][i * 16 + l16][quad * 8]);
#pragma unroll
            for (int j = 0; j < 2; j++)
                bfr[j] = *reinterpret_cast<const bf16x8*>(&Bs[(wave * 32 + j * 16 + l16) * 32 + quad * 8]);
#pragma unroll
            for (int i = 0; i < 4; i++)
#pragma unroll
                for (int j = 0; j < 2; j++)
                    acc[i][j] = __builtin_amdgcn_mfma_f32_16x16x32_bf16(af[i], bfr[j], acc[i][j], 0, 0, 0);
            __syncthreads();
        }
        // epilogue: relu + per-block (sum, max) partials for this column chunk
        size_t pbase = ((size_t)blockIdx.x * 4 + nt) * 256;
#pragma unroll
        for (int j = 0; j < 2; j++) {
            int f128 = wave * 32 + j * 16 + l16;
            float bv = bias[nt * 128 + f128];
            float s = 0.f, mx = 0.f;
#pragma unroll
            for (int i = 0; i < 4; i++)
#pragma unroll
                for (int r = 0; r < 4; r++) {
                    float v = fmaxf(acc[i][j][r] + bv, 0.f);
                    s += v;
                    mx = fmaxf(mx, v);
                }
            s += __shfl_xor(s, 16);
            s += __shfl_xor(s, 32);
            mx = fmaxf(mx, __shfl_xor(mx, 16));
            mx = fmaxf(mx, __shfl_xor(mx, 32));
            if (quad == 0) {
                partials[pbase + f128] = s;
                partials[pbase + 128 + f128] = mx;
            }
        }
    }
}

// ---------- final pool: combine 16 row-tiles per graph -> mean/max ----------
__global__ __launch_bounds__(256) void k_pool_final(const float* __restrict__ partials,
                                                    float* __restrict__ pooled) {
    int idx = blockIdx.x * 256 + threadIdx.x;  // over 64*512
    int g = idx >> 9, f = idx & 511;
    int by = f >> 7, f128 = f & 127;
    float S = 0.f, M = 0.f;
#pragma unroll
    for (int tile = 0; tile < 16; ++tile) {
        size_t pbase = ((size_t)(g * 16 + tile) * 4 + by) * 256;
        S += partials[pbase + f128];
        M = fmaxf(M, partials[pbase + 128 + f128]);
    }
    pooled[g * 1024 + f] = S * (1.0f / 1024.0f);
    pooled[g * 1024 + 512 + f] = M;
}

// ---------- MLP head ----------
__global__ __launch_bounds__(256) void k_mlp1(const float* __restrict__ pooled,
                                              const float* __restrict__ Wm1,
                                              const float* __restrict__ bm1,
                                              float* __restrict__ o) {
    __shared__ float hg[1024];
    __shared__ float red[256];
    int g = blockIdx.x;
    int t = threadIdx.x;
    int f64 = t & 63, kq = t >> 6;
    int f = blockIdx.y * 64 + f64;
#pragma unroll
    for (int i = 0; i < 4; i++) hg[t + i * 256] = pooled[g * 1024 + t + i * 256];
    __syncthreads();
    float acc = 0.f;
    int k0 = kq * 256;
#pragma unroll 8
    for (int k = k0; k < k0 + 256; ++k)
        acc += hg[k] * Wm1[(size_t)k * 512 + f];
    red[t] = acc;
    __syncthreads();
    if (t < 64) {
        float total = red[t] + red[t + 64] + red[t + 128] + red[t + 192] + bm1[f];
        o[g * 512 + f] = fmaxf(total, 0.f);
    }
}

__global__ __launch_bounds__(512) void k_mlp2(const float* __restrict__ h,
                                              const float* __restrict__ Wm2,
                                              const float* __restrict__ bm2,
                                              float* __restrict__ out) {
    int g = blockIdx.x;
    int t = threadIdx.x;
    int j = t >> 5, lane32 = t & 31;
    float acc = 0.f;
    if (j < 10) {
        int k0 = lane32 * 16;
#pragma unroll
        for (int i = 0; i < 16; ++i)
            acc += h[g * 512 + k0 + i] * Wm2[(size_t)(k0 + i) * 10 + j];
    }
#pragma unroll
    for (int m = 16; m >= 1; m >>= 1) acc += __shfl_xor(acc, m);
    if (j < 10 && lane32 == 0) out[g * 10 + j] = acc + bm2[j];
}

extern "C" void kernel_launch(void* const* d_in, const int* in_sizes, int n_in,
                              void* d_out, int out_size, void* d_ws, size_t ws_size,
                              hipStream_t stream) {
    const float* x   = (const float*)d_in[0];
    const int*   ei  = (const int*)d_in[1];
    const float* W1  = (const float*)d_in[3];
    const float* b1  = (const float*)d_in[4];
    const float* W2  = (const float*)d_in[5];
    const float* b2  = (const float*)d_in[6];
    const float* W3  = (const float*)d_in[7];
    const float* b3  = (const float*)d_in[8];
    const float* Wm1 = (const float*)d_in[9];
    const float* bm1 = (const float*)d_in[10];
    const float* Wm2 = (const float*)d_in[11];
    const float* bm2 = (const float*)d_in[12];
    float* out = (float*)d_out;

    const int N = in_sizes[0] / 3;  // 65536
    const int E = in_sizes[1] / 2;  // 524288
    const int* row = ei;
    const int* col = ei + E;

    char* ws = (char*)d_ws;
    size_t off = 0;
    auto alloc = [&](size_t bytes) {
        void* p = ws + off;
        off += (bytes + 255) & ~(size_t)255;
        return p;
    };
    int*   cnt      = (int*)alloc((size_t)N * 4);
    int*   rowptr   = (int*)alloc((size_t)N * 4);
    int*   fill     = (int*)alloc((size_t)N * 4);
    float* dinv     = (float*)alloc((size_t)N * 4);
    int*   bsum     = (int*)alloc(256 * 4);
    int*   boff     = (int*)alloc(256 * 4);
    int2*  adj      = (int2*)alloc((size_t)E * 8);
    float* agg1     = (float*)alloc((size_t)N * 3 * 4);
    bf16*  h1       = (bf16*)alloc((size_t)N * 64 * 2);
    bf16*  agg2     = (bf16*)alloc((size_t)N * 64 * 2);
    bf16*  h2       = (bf16*)alloc((size_t)N * 256 * 2);
    bf16*  WT2      = (bf16*)alloc(256 * 64 * 2);
    bf16*  WT3      = (bf16*)alloc(512 * 256 * 2);
    float* partials = (float*)alloc((size_t)1024 * 4 * 256 * 4);  // 4 MB
    float* pooled   = (float*)alloc(64 * 1024 * 4);
    float* m1       = (float*)alloc(64 * 512 * 4);

    // ---- CSR build (once; reused by all 3 layers) ----
    hipMemsetAsync(cnt, 0, (size_t)N * 4, stream);
    hipMemsetAsync(fill, 0, (size_t)N * 4, stream);
    k_count<<<(E + 255) / 256, 256, 0, stream>>>(col, cnt, E);
    k_rsqrt<<<(N + 255) / 256, 256, 0, stream>>>(cnt, dinv, N);
    k_scan_a<<<256, 256, 0, stream>>>(cnt, bsum);
    k_scan_b<<<1, 256, 0, stream>>>(bsum, boff);
    k_scan_c<<<256, 256, 0, stream>>>(cnt, boff, rowptr);
    k_scatter<<<(E + 255) / 256, 256, 0, stream>>>(row, col, dinv, rowptr, fill, adj, E);

    // ---- weight prep ----
    k_prep<<<(64 * 256 + 255) / 256, 256, 0, stream>>>(W2, WT2, 64, 256);
    k_prep<<<(256 * 512 + 255) / 256, 256, 0, stream>>>(W3, WT3, 256, 512);

    // ---- layer 1: gather x (F=3), then 3->64 GEMM + bias + relu ----
    k_gather_x<<<(N + 255) / 256, 256, 0, stream>>>(adj, rowptr, cnt, dinv, x, agg1, N);
    k_gemm1<<<(N * 64) / 256, 256, 0, stream>>>(agg1, W1, b1, h1, N);

    // ---- layer 2: gather h1 (F=64, 8 lanes/node), then 64->256 MFMA GEMM ----
    k_gather_pre<64><<<(N * 8) / 256, 256, 0, stream>>>(adj, rowptr, cnt, dinv, h1, agg2, N);
    k_gemm_br<<<dim3(N / 128, 256 / 128), 256, 0, stream>>>(agg2, WT2, b2, h2, N, 256, 64);

    // ---- layer 3: fused gather + 256->512 MFMA + pool partials ----
    k_gcn3<<<N / 64, 256, 0, stream>>>(adj, rowptr, cnt, dinv, h2, WT3, b3, partials);
    k_pool_final<<<(64 * 512) / 256, 256, 0, stream>>>(partials, pooled);

    // ---- MLP head ----
    k_mlp1<<<dim3(64, 8), 256, 0, stream>>>(pooled, Wm1, bm1, m1);
    k_mlp2<<<64, 512, 0, stream>>>(m1, Wm2, bm2, out);
}

// Round 11
// 273.528 us; speedup vs baseline: 1.1043x; 1.1043x over previous
//
#include <hip/hip_runtime.h>
#include <hip/hip_bf16.h>

typedef __hip_bfloat16 bf16;
typedef short bf16x8 __attribute__((ext_vector_type(8)));
typedef float f32x4 __attribute__((ext_vector_type(4)));

// ---------- helpers ----------
__device__ __forceinline__ float b2f_us(unsigned short u) {
    union { unsigned int i; float f; } c;
    c.i = ((unsigned int)u) << 16;
    return c.f;
}
__device__ __forceinline__ unsigned short f2b_us(float f) {
    bf16 h = __float2bfloat16(f);
    return *reinterpret_cast<unsigned short*>(&h);
}
__device__ __forceinline__ void unpack8(uint4 p, float* f) {
    f[0] = b2f_us(p.x & 0xffff); f[1] = b2f_us(p.x >> 16);
    f[2] = b2f_us(p.y & 0xffff); f[3] = b2f_us(p.y >> 16);
    f[4] = b2f_us(p.z & 0xffff); f[5] = b2f_us(p.z >> 16);
    f[6] = b2f_us(p.w & 0xffff); f[7] = b2f_us(p.w >> 16);
}

// async 16B global -> LDS (global_load_lds_dwordx4)
__device__ __forceinline__ void async_copy16(const bf16* g, bf16* l) {
    __builtin_amdgcn_global_load_lds(
        (const __attribute__((address_space(1))) unsigned int*)g,
        (__attribute__((address_space(3))) unsigned int*)l, 16, 0, 0);
}

// ---------- CSR build ----------
__global__ __launch_bounds__(256) void k_count(const int* __restrict__ col,
                                               int* __restrict__ cnt, int E) {
    int e = blockIdx.x * 256 + threadIdx.x;
    if (e < E) atomicAdd(cnt + col[e], 1);
}
// block partial sums for scan + dinv = rsqrt(cnt+1)
__global__ __launch_bounds__(256) void k_scan_a(const int* __restrict__ cnt,
                                                int* __restrict__ bsum,
                                                float* __restrict__ dinv) {
    __shared__ int s[256];
    int t = threadIdx.x;
    int i = blockIdx.x * 256 + t;
    int c = cnt[i];
    dinv[i] = rsqrtf((float)c + 1.0f);  // +1 self-loop
    s[t] = c;
    __syncthreads();
#pragma unroll
    for (int off = 128; off >= 1; off >>= 1) {
        if (t < off) s[t] += s[t + off];
        __syncthreads();
    }
    if (t == 0) bsum[blockIdx.x] = s[0];
}
__global__ __launch_bounds__(256) void k_scan_b(const int* __restrict__ bsum,
                                                int* __restrict__ boff) {
    __shared__ int s[256];
    int t = threadIdx.x;
    int self = bsum[t];
    s[t] = self;
    __syncthreads();
#pragma unroll
    for (int off = 1; off < 256; off <<= 1) {
        int v = (t >= off) ? s[t - off] : 0;
        __syncthreads();
        s[t] += v;
        __syncthreads();
    }
    boff[t] = s[t] - self;  // exclusive
}
__global__ __launch_bounds__(256) void k_scan_c(const int* __restrict__ cnt,
                                                const int* __restrict__ boff,
                                                int* __restrict__ rowptr) {
    __shared__ int s[256];
    int t = threadIdx.x;
    int base = blockIdx.x * 256;
    int self = cnt[base + t];
    s[t] = self;
    __syncthreads();
#pragma unroll
    for (int off = 1; off < 256; off <<= 1) {
        int v = (t >= off) ? s[t - off] : 0;
        __syncthreads();
        s[t] += v;
        __syncthreads();
    }
    rowptr[base + t] = boff[blockIdx.x] + s[t] - self;  // exclusive
}

__global__ __launch_bounds__(256) void k_scatter(const int* __restrict__ row,
                                                 const int* __restrict__ col,
                                                 const float* __restrict__ dinv,
                                                 const int* __restrict__ rowptr,
                                                 int* __restrict__ fill,
                                                 int2* __restrict__ adj, int E) {
    int e = blockIdx.x * 256 + threadIdx.x;
    if (e >= E) return;
    int r = row[e], c = col[e];
    int pos = rowptr[c] + atomicAdd(fill + c, 1);
    adj[pos] = make_int2(r, __float_as_int(dinv[r]));
}

// ---------- weight prep (both layers in one launch): W[K,N] f32 -> WT[N,K] bf16 ----------
__global__ __launch_bounds__(256) void k_prep_all(const float* __restrict__ W2,
                                                  bf16* __restrict__ WT2,
                                                  const float* __restrict__ W3,
                                                  bf16* __restrict__ WT3) {
    int idx = blockIdx.x * 256 + threadIdx.x;
    if (idx < 64 * 256) {
        int k = idx >> 8, n = idx & 255;           // K=64, N=256
        WT2[n * 64 + k] = __float2bfloat16(W2[idx]);
    } else {
        int i = idx - 64 * 256;
        if (i < 256 * 512) {
            int k = i >> 9, n = i & 511;           // K=256, N=512
            WT3[(size_t)n * 256 + k] = __float2bfloat16(W3[i]);
        }
    }
}

// ---------- FUSED layer 1: gather x (F=3) + 3->64 GEMM + bias + relu -> h1 ----------
__global__ __launch_bounds__(256) void k_gcn1(const int2* __restrict__ adj,
                                              const int* __restrict__ rowptr,
                                              const int* __restrict__ cnt,
                                              const float* __restrict__ dinv,
                                              const float* __restrict__ x,
                                              const float* __restrict__ W,
                                              const float* __restrict__ bias,
                                              bf16* __restrict__ h1, int N) {
    __shared__ float w[256];
    int t = threadIdx.x;
    if (t < 192) w[t] = W[t];
    else w[t] = bias[t - 192];
    __syncthreads();
    int n = blockIdx.x * 256 + t;
    if (n >= N) return;
    float d = dinv[n];
    float d2 = d * d;
    float a0 = x[n * 3] * d2, a1 = x[n * 3 + 1] * d2, a2 = x[n * 3 + 2] * d2;
    int beg = rowptr[n], end = beg + cnt[n];
    for (int e = beg; e < end; ++e) {
        int2 ad = adj[e];
        float wt = __int_as_float(ad.y) * d;
        a0 += x[ad.x * 3] * wt;
        a1 += x[ad.x * 3 + 1] * wt;
        a2 += x[ad.x * 3 + 2] * wt;
    }
    bf16* dst = h1 + (size_t)n * 64;
#pragma unroll
    for (int fb = 0; fb < 8; ++fb) {
        uint4 r;
        unsigned v[4];
#pragma unroll
        for (int p = 0; p < 4; ++p) {
            int f0 = fb * 8 + p * 2;
            float u0 = fmaxf(a0 * w[f0] + a1 * w[64 + f0] + a2 * w[128 + f0] + w[192 + f0], 0.f);
            int f1 = f0 + 1;
            float u1 = fmaxf(a0 * w[f1] + a1 * w[64 + f1] + a2 * w[128 + f1] + w[192 + f1], 0.f);
            v[p] = (unsigned)f2b_us(u0) | ((unsigned)f2b_us(u1) << 16);
        }
        r.x = v[0]; r.y = v[1]; r.z = v[2]; r.w = v[3];
        *reinterpret_cast<uint4*>(dst + fb * 8) = r;
    }
}

// ---------- CSR gather (bf16 -> bf16, incl. self; 8 feats/lane, 8-edge unroll) ----------
template <int F>
__global__ __launch_bounds__(256, 4) void k_gather_pre(const int2* __restrict__ adj,
                                                       const int* __restrict__ rowptr,
                                                       const int* __restrict__ cnt,
                                                       const float* __restrict__ dinv,
                                                       const bf16* __restrict__ h,
                                                       bf16* __restrict__ agg, int N) {
    constexpr int LPN = F / 8;           // lanes per node, 8 feats (16B) each
    constexpr int NPB = 256 / LPN;       // nodes per block
    int t = threadIdx.x;
    int node = blockIdx.x * NPB + t / LPN;
    if (node >= N) return;
    int fbase = (t % LPN) * 8;
    float d = dinv[node];
    size_t sbase = (size_t)node * F + fbase;
    uint4 sp = *reinterpret_cast<const uint4*>(h + sbase);
    float a[8];
    unpack8(sp, a);
    float d2 = d * d;
#pragma unroll
    for (int i = 0; i < 8; i++) a[i] *= d2;
    int beg = rowptr[node];
    int end = beg + cnt[node];
    int e = beg;
    for (; e + 7 < end; e += 8) {
        int2 ad[8];
        uint4 p[8];
#pragma unroll
        for (int u = 0; u < 8; ++u) ad[u] = adj[e + u];
#pragma unroll
        for (int u = 0; u < 8; ++u)
            p[u] = *reinterpret_cast<const uint4*>(h + (size_t)ad[u].x * F + fbase);
#pragma unroll
        for (int u = 0; u < 8; ++u) {
            float wt = __int_as_float(ad[u].y) * d;
            float f[8];
            unpack8(p[u], f);
#pragma unroll
            for (int i = 0; i < 8; i++) a[i] += f[i] * wt;
        }
    }
    for (; e + 3 < end; e += 4) {
        int2 ad[4];
        uint4 p[4];
#pragma unroll
        for (int u = 0; u < 4; ++u) ad[u] = adj[e + u];
#pragma unroll
        for (int u = 0; u < 4; ++u)
            p[u] = *reinterpret_cast<const uint4*>(h + (size_t)ad[u].x * F + fbase);
#pragma unroll
        for (int u = 0; u < 4; ++u) {
            float wt = __int_as_float(ad[u].y) * d;
            float f[8];
            unpack8(p[u], f);
#pragma unroll
            for (int i = 0; i < 8; i++) a[i] += f[i] * wt;
        }
    }
    for (; e < end; ++e) {
        int2 ad = adj[e];
        float wt = __int_as_float(ad.y) * d;
        uint4 p = *reinterpret_cast<const uint4*>(h + (size_t)ad.x * F + fbase);
        float f[8];
        unpack8(p, f);
#pragma unroll
        for (int i = 0; i < 8; i++) a[i] += f[i] * wt;
    }
    uint4 r;
    r.x = (unsigned)f2b_us(a[0]) | ((unsigned)f2b_us(a[1]) << 16);
    r.y = (unsigned)f2b_us(a[2]) | ((unsigned)f2b_us(a[3]) << 16);
    r.z = (unsigned)f2b_us(a[4]) | ((unsigned)f2b_us(a[5]) << 16);
    r.w = (unsigned)f2b_us(a[6]) | ((unsigned)f2b_us(a[7]) << 16);
    *reinterpret_cast<uint4*>(agg + sbase) = r;
}

// ---------- MFMA GEMM + bias + relu: C = relu(A @ BT^T + b), bf16 out ----------
__global__ __launch_bounds__(256) void k_gemm_br(const bf16* __restrict__ A,
                                                 const bf16* __restrict__ BT,
                                                 const float* __restrict__ bias,
                                                 bf16* __restrict__ C,
                                                 int M, int N, int K) {
    __shared__ bf16 As[128 * 32];
    __shared__ bf16 Bs[128 * 32];
    const int t = threadIdx.x;
    const int wave = t >> 6, lane = t & 63;
    const int quad = lane >> 4, l16 = lane & 15;
    const int wm = wave & 1, wn = wave >> 1;
    const int m0 = blockIdx.x * 128;
    const int n0 = blockIdx.y * 128;

    f32x4 acc[4][4] = {};
    for (int kb = 0; kb < K; kb += 32) {
#pragma unroll
        for (int rnd = 0; rnd < 2; ++rnd) {
            int c = (rnd * 4 + wave) * 64 + lane;
            int r = c >> 2, seg = c & 3;
            async_copy16(A + (size_t)(m0 + r) * K + kb + seg * 8, As + c * 8);
            async_copy16(BT + (size_t)(n0 + r) * K + kb + seg * 8, Bs + c * 8);
        }
        __syncthreads();
        bf16x8 af[4], bfr[4];
#pragma unroll
        for (int i = 0; i < 4; i++)
            af[i] = *reinterpret_cast<const bf16x8*>(&As[(wm * 64 + i * 16 + l16) * 32 + quad * 8]);
#pragma unroll
        for (int j = 0; j < 4; j++)
            bfr[j] = *reinterpret_cast<const bf16x8*>(&Bs[(wn * 64 + j * 16 + l16) * 32 + quad * 8]);
#pragma unroll
        for (int i = 0; i < 4; i++)
#pragma unroll
            for (int j = 0; j < 4; j++)
                acc[i][j] = __builtin_amdgcn_mfma_f32_16x16x32_bf16(af[i], bfr[j], acc[i][j], 0, 0, 0);
        __syncthreads();
    }
#pragma unroll
    for (int j = 0; j < 4; j++) {
        int cn = n0 + wn * 64 + j * 16 + l16;
        float bv = bias[cn];
#pragma unroll
        for (int i = 0; i < 4; i++) {
            int row = m0 + wm * 64 + i * 16 + quad * 4;
#pragma unroll
            for (int r = 0; r < 4; r++)
                C[(size_t)(row + r) * N + cn] = __float2bfloat16(fmaxf(acc[i][j][r] + bv, 0.f));
        }
    }
}

// ---------- MFMA GEMM + bias + relu + per-block pool partials (no atomics) ----------
__global__ __launch_bounds__(256) void k_gemm_pool(const bf16* __restrict__ A,
                                                   const bf16* __restrict__ BT,
                                                   const float* __restrict__ bias,
                                                   float* __restrict__ partials,
                                                   int M, int N, int K) {
    __shared__ bf16 As[128 * 32];
    __shared__ bf16 Bs[128 * 32];
    const int t = threadIdx.x;
    const int wave = t >> 6, lane = t & 63;
    const int quad = lane >> 4, l16 = lane & 15;
    const int wm = wave & 1, wn = wave >> 1;
    const int m0 = blockIdx.x * 128;
    const int n0 = blockIdx.y * 128;

    f32x4 acc[4][4] = {};
    for (int kb = 0; kb < K; kb += 32) {
#pragma unroll
        for (int rnd = 0; rnd < 2; ++rnd) {
            int c = (rnd * 4 + wave) * 64 + lane;
            int r = c >> 2, seg = c & 3;
            async_copy16(A + (size_t)(m0 + r) * K + kb + seg * 8, As + c * 8);
            async_copy16(BT + (size_t)(n0 + r) * K + kb + seg * 8, Bs + c * 8);
        }
        __syncthreads();
        bf16x8 af[4], bfr[4];
#pragma unroll
        for (int i = 0; i < 4; i++)
            af[i] = *reinterpret_cast<const bf16x8*>(&As[(wm * 64 + i * 16 + l16) * 32 + quad * 8]);
#pragma unroll
        for (int j = 0; j < 4; j++)
            bfr[j] = *reinterpret_cast<const bf16x8*>(&Bs[(wn * 64 + j * 16 + l16) * 32 + quad * 8]);
#pragma unroll
        for (int i = 0; i < 4; i++)
#pragma unroll
            for (int j = 0; j < 4; j++)
                acc[i][j] = __builtin_amdgcn_mfma_f32_16x16x32_bf16(af[i], bfr[j], acc[i][j], 0, 0, 0);
        __syncthreads();
    }
    size_t pbase = ((size_t)(blockIdx.x * 4 + blockIdx.y) * 2 + wm) * 256;
#pragma unroll
    for (int j = 0; j < 4; j++) {
        int f128 = wn * 64 + j * 16 + l16;
        float bv = bias[n0 + f128];
        float s = 0.f, mx = 0.f;
#pragma unroll
        for (int i = 0; i < 4; i++)
#pragma unroll
            for (int r = 0; r < 4; r++) {
                float v = fmaxf(acc[i][j][r] + bv, 0.f);
                s += v;
                mx = fmaxf(mx, v);
            }
        s += __shfl_xor(s, 16);
        s += __shfl_xor(s, 32);
        mx = fmaxf(mx, __shfl_xor(mx, 16));
        mx = fmaxf(mx, __shfl_xor(mx, 32));
        if (quad == 0) {
            partials[pbase + f128] = s;
            partials[pbase + 128 + f128] = mx;
        }
    }
}

// ---------- final pool: combine 8 m-tiles x 2 wave-halves -> mean/max ----------
__global__ __launch_bounds__(256) void k_pool_final(const float* __restrict__ partials,
                                                    float* __restrict__ pooled) {
    int idx = blockIdx.x * 256 + threadIdx.x;  // over 64*512
    int g = idx >> 9, f = idx & 511;
    int by = f >> 7, f128 = f & 127;
    float S = 0.f, M = 0.f;
#pragma unroll
    for (int tile = 0; tile < 8; ++tile) {
        int bx = g * 8 + tile;
#pragma unroll
        for (int wm = 0; wm < 2; ++wm) {
            size_t pbase = ((size_t)(bx * 4 + by) * 2 + wm) * 256;
            S += partials[pbase + f128];
            M = fmaxf(M, partials[pbase + 128 + f128]);
        }
    }
    pooled[g * 1024 + f] = S * (1.0f / 1024.0f);
    pooled[g * 1024 + 512 + f] = M;
}

// ---------- MLP head ----------
__global__ __launch_bounds__(256) void k_mlp1(const float* __restrict__ pooled,
                                              const float* __restrict__ Wm1,
                                              const float* __restrict__ bm1,
                                              float* __restrict__ o) {
    __shared__ float hg[1024];
    __shared__ float red[256];
    int g = blockIdx.x;
    int t = threadIdx.x;
    int f64 = t & 63, kq = t >> 6;
    int f = blockIdx.y * 64 + f64;
#pragma unroll
    for (int i = 0; i < 4; i++) hg[t + i * 256] = pooled[g * 1024 + t + i * 256];
    __syncthreads();
    float acc = 0.f;
    int k0 = kq * 256;
#pragma unroll 8
    for (int k = k0; k < k0 + 256; ++k)
        acc += hg[k] * Wm1[(size_t)k * 512 + f];
    red[t] = acc;
    __syncthreads();
    if (t < 64) {
        float total = red[t] + red[t + 64] + red[t + 128] + red[t + 192] + bm1[f];
        o[g * 512 + f] = fmaxf(total, 0.f);
    }
}

__global__ __launch_bounds__(512) void k_mlp2(const float* __restrict__ h,
                                              const float* __restrict__ Wm2,
                                              const float* __restrict__ bm2,
                                              float* __restrict__ out) {
    int g = blockIdx.x;
    int t = threadIdx.x;
    int j = t >> 5, lane32 = t & 31;
    float acc = 0.f;
    if (j < 10) {
        int k0 = lane32 * 16;
#pragma unroll
        for (int i = 0; i < 16; ++i)
            acc += h[g * 512 + k0 + i] * Wm2[(size_t)(k0 + i) * 10 + j];
    }
#pragma unroll
    for (int m = 16; m >= 1; m >>= 1) acc += __shfl_xor(acc, m);
    if (j < 10 && lane32 == 0) out[g * 10 + j] = acc + bm2[j];
}

extern "C" void kernel_launch(void* const* d_in, const int* in_sizes, int n_in,
                              void* d_out, int out_size, void* d_ws, size_t ws_size,
                              hipStream_t stream) {
    const float* x   = (const float*)d_in[0];
    const int*   ei  = (const int*)d_in[1];
    const float* W1  = (const float*)d_in[3];
    const float* b1  = (const float*)d_in[4];
    const float* W2  = (const float*)d_in[5];
    const float* b2  = (const float*)d_in[6];
    const float* W3  = (const float*)d_in[7];
    const float* b3  = (const float*)d_in[8];
    const float* Wm1 = (const float*)d_in[9];
    const float* bm1 = (const float*)d_in[10];
    const float* Wm2 = (const float*)d_in[11];
    const float* bm2 = (const float*)d_in[12];
    float* out = (float*)d_out;

    const int N = in_sizes[0] / 3;  // 65536
    const int E = in_sizes[1] / 2;  // 524288
    const int* row = ei;
    const int* col = ei + E;

    char* ws = (char*)d_ws;
    size_t off = 0;
    auto alloc = [&](size_t bytes) {
        void* p = ws + off;
        off += (bytes + 255) & ~(size_t)255;
        return p;
    };
    int*   cnt      = (int*)alloc((size_t)N * 4);   // cnt & fill adjacent: one memset
    int*   fill     = (int*)alloc((size_t)N * 4);
    int*   rowptr   = (int*)alloc((size_t)N * 4);
    float* dinv     = (float*)alloc((size_t)N * 4);
    int*   bsum     = (int*)alloc(256 * 4);
    int*   boff     = (int*)alloc(256 * 4);
    int2*  adj      = (int2*)alloc((size_t)E * 8);
    bf16*  h1       = (bf16*)alloc((size_t)N * 64 * 2);
    bf16*  agg2     = (bf16*)alloc((size_t)N * 64 * 2);
    bf16*  h2       = (bf16*)alloc((size_t)N * 256 * 2);
    bf16*  agg3     = (bf16*)alloc((size_t)N * 256 * 2);
    bf16*  WT2      = (bf16*)alloc(256 * 64 * 2);
    bf16*  WT3      = (bf16*)alloc(512 * 256 * 2);
    float* partials = (float*)alloc((size_t)512 * 4 * 2 * 256 * 4);  // 4 MB
    float* pooled   = (float*)alloc(64 * 1024 * 4);
    float* m1       = (float*)alloc(64 * 512 * 4);

    // ---- CSR build (once; reused by all 3 layers) ----
    hipMemsetAsync(cnt, 0, (size_t)N * 8, stream);  // cnt + fill in one shot
    k_count<<<(E + 255) / 256, 256, 0, stream>>>(col, cnt, E);
    k_scan_a<<<256, 256, 0, stream>>>(cnt, bsum, dinv);
    k_scan_b<<<1, 256, 0, stream>>>(bsum, boff);
    k_scan_c<<<256, 256, 0, stream>>>(cnt, boff, rowptr);
    k_scatter<<<(E + 255) / 256, 256, 0, stream>>>(row, col, dinv, rowptr, fill, adj, E);

    // ---- weight prep (single launch) ----
    k_prep_all<<<(64 * 256 + 256 * 512 + 255) / 256, 256, 0, stream>>>(W2, WT2, W3, WT3);

    // ---- layer 1: fused gather(F=3) + 3->64 GEMM + bias + relu ----
    k_gcn1<<<(N + 255) / 256, 256, 0, stream>>>(adj, rowptr, cnt, dinv, x, W1, b1, h1, N);

    // ---- layer 2: gather h1 (F=64), then 64->256 MFMA GEMM + bias + relu ----
    k_gather_pre<64><<<(N * 8) / 256, 256, 0, stream>>>(adj, rowptr, cnt, dinv, h1, agg2, N);
    k_gemm_br<<<dim3(N / 128, 256 / 128), 256, 0, stream>>>(agg2, WT2, b2, h2, N, 256, 64);

    // ---- layer 3: gather h2 (F=256), then 256->512 MFMA GEMM + pool partials ----
    k_gather_pre<256><<<(N * 32) / 256, 256, 0, stream>>>(adj, rowptr, cnt, dinv, h2, agg3, N);
    k_gemm_pool<<<dim3(N / 128, 512 / 128), 256, 0, stream>>>(agg3, WT3, b3, partials, N, 512, 256);
    k_pool_final<<<(64 * 512) / 256, 256, 0, stream>>>(partials, pooled);

    // ---- MLP head ----
    k_mlp1<<<dim3(64, 8), 256, 0, stream>>>(pooled, Wm1, bm1, m1);
    k_mlp2<<<64, 512, 0, stream>>>(m1, Wm2, bm2, out);
}